// Round 5
// baseline (110.169 us; speedup 1.0000x reference)
//
#include <hip/hip_runtime.h>
#include <hip/hip_bf16.h>

#define B_     32
#define N_     16384
#define D_     64
#define C_     36
#define CP_    48     // padded cluster count (3 x 16 MFMA tiles)
#define FG_    32
#define ALPHA_ 10.0f
#define NB_    32     // n-blocks per batch -> grid 1024
#define RPB_   (N_/NB_)   // 512 rows per block
#define UNITS_ 4          // per wave: 4 units x 32 rows = 128 rows

typedef __attribute__((ext_vector_type(8))) short bf16x8;
typedef __attribute__((ext_vector_type(4))) short bf16x4;
typedef __attribute__((ext_vector_type(4))) float f32x4;

#define MFMA(a,b,c) __builtin_amdgcn_mfma_f32_16x16x32_bf16(a,b,c,0,0,0)

__device__ __forceinline__ unsigned short f2bf(float f){
  unsigned u = __float_as_uint(f);
  unsigned r = u + 0x7fffu + ((u >> 16) & 1u);   // RNE; inputs finite
  return (unsigned short)(r >> 16);
}
__device__ __forceinline__ float bf2f(unsigned short u){
  return __uint_as_float((unsigned)u << 16);
}

// v -> hi bf16 (slot J of H) + residual lo bf16 (slot J of L)
#define CVT1(v, H, L, J) { unsigned short hb_ = f2bf(v); (H)[J] = (short)hb_; \
  (L)[J] = (short)f2bf((v) - bf2f(hb_)); }

__device__ __forceinline__ bf16x8 ld_frag(const unsigned short* p){
  bf16x4 a = *(const bf16x4*)p;
  bf16x4 b = *(const bf16x4*)(p + 4);
  return __builtin_shufflevector(a, b, 0,1,2,3,4,5,6,7);
}

// ---------------------------------------------------------------------------
// Fused kernel. grid = 1024 (32 batches x 32 n-blocks), block = 256 = 4 waves.
// Wave owns 128 rows: 4 units of 32 rows (2 groups of 16).
// Per 16-row group: global load (prefetched 2 groups ahead) -> row norm ->
//   bf16 hi/lo frags -> cos MFMA -> softmax -> asg/x^T staged to LDS
//   (proven round-2 transposed layout, pitch 36).
// Per unit: ws MFMA with A(asg),B(x^T) fragments via b64 LDS reads.
// NPART==NB_: non-atomic per-block partials; NPART==1: atomic fallback.
// ---------------------------------------------------------------------------
template<int NPART>
__global__ __launch_bounds__(256, 2) void k_accum(
    const float* __restrict__ x, const float* __restrict__ cent,
    float* __restrict__ wsP, float* __restrict__ spP)
{
  const int t   = threadIdx.x;
  const int wid = t >> 6;
  const int l   = t & 63;
  const int lm  = l & 15;
  const int lg  = l >> 4;
  const int b   = blockIdx.x >> 5;
  const int nb  = blockIdx.x & 31;

  __shared__ float nrmc[C_];
  __shared__ float spR[CP_];
  __shared__ __align__(16) union {
    struct { unsigned short asg[4][CP_*36]; unsigned short xt[4][64*36]; } m; // 32256 B
    float red[2][CP_*65];                                                     // 24960 B
  } sh;

  if (t < C_) {
    float ss = 0.f;
    for (int d = 0; d < D_; ++d) { float v = cent[d*C_ + t]; ss = fmaf(v, v, ss); }
    nrmc[t] = rsqrtf(fmaxf(ss, 1e-24f));
  }
  __syncthreads();

  // normalized-centroid A-fragments: A[m=c][k=d], c = 16*ct+lm, d = 32*s+8*lg+j
  bf16x8 cnf[3][2];
  #pragma unroll
  for (int ct = 0; ct < 3; ++ct) {
    #pragma unroll
    for (int s = 0; s < 2; ++s) {
      bf16x8 f;
      #pragma unroll
      for (int j = 0; j < 8; ++j) {
        int d = 32*s + 8*lg + j;
        int c = 16*ct + lm;
        float v = (c < C_) ? cent[d*C_ + c] * nrmc[c] : 0.f;
        f[j] = (short)f2bf(v);
      }
      cnf[ct][s] = f;
    }
  }

  f32x4 acc[3][4];
  #pragma unroll
  for (int ct = 0; ct < 3; ++ct)
    #pragma unroll
    for (int nt = 0; nt < 4; ++nt) acc[ct][nt] = (f32x4){0.f,0.f,0.f,0.f};
  float sp[3][4];
  #pragma unroll
  for (int ct = 0; ct < 3; ++ct)
    #pragma unroll
    for (int r = 0; r < 4; ++r) sp[ct][r] = 0.f;

  unsigned short* aw = sh.m.asg[wid];
  unsigned short* xw = sh.m.xt[wid];

  // per-16-row-group staging: lane holds row lm, float cols {8lg..+7, 32+8lg..+7}
  auto process = [&](float4 c0, float4 c1, float4 c2, float4 c3, int g2) {
    float ss = 0.f;
    ss = fmaf(c0.x,c0.x,ss); ss = fmaf(c0.y,c0.y,ss); ss = fmaf(c0.z,c0.z,ss); ss = fmaf(c0.w,c0.w,ss);
    ss = fmaf(c1.x,c1.x,ss); ss = fmaf(c1.y,c1.y,ss); ss = fmaf(c1.z,c1.z,ss); ss = fmaf(c1.w,c1.w,ss);
    ss = fmaf(c2.x,c2.x,ss); ss = fmaf(c2.y,c2.y,ss); ss = fmaf(c2.z,c2.z,ss); ss = fmaf(c2.w,c2.w,ss);
    ss = fmaf(c3.x,c3.x,ss); ss = fmaf(c3.y,c3.y,ss); ss = fmaf(c3.z,c3.z,ss); ss = fmaf(c3.w,c3.w,ss);
    ss += __shfl_xor(ss, 16);
    ss += __shfl_xor(ss, 32);
    float rn = rsqrtf(fmaxf(ss, 1e-24f));

    bf16x8 bh0, bl0, bh1, bl1;
    CVT1(c0.x,bh0,bl0,0) CVT1(c0.y,bh0,bl0,1) CVT1(c0.z,bh0,bl0,2) CVT1(c0.w,bh0,bl0,3)
    CVT1(c1.x,bh0,bl0,4) CVT1(c1.y,bh0,bl0,5) CVT1(c1.z,bh0,bl0,6) CVT1(c1.w,bh0,bl0,7)
    CVT1(c2.x,bh1,bl1,0) CVT1(c2.y,bh1,bl1,1) CVT1(c2.z,bh1,bl1,2) CVT1(c2.w,bh1,bl1,3)
    CVT1(c3.x,bh1,bl1,4) CVT1(c3.y,bh1,bl1,5) CVT1(c3.z,bh1,bl1,6) CVT1(c3.w,bh1,bl1,7)

    // cos GEMM: D[m=c][n=row] = cn . x (raw x; rn applied after)
    f32x4 q0 = (f32x4){0,0,0,0}, q1 = (f32x4){0,0,0,0}, q2 = (f32x4){0,0,0,0};
    q0 = MFMA(cnf[0][0], bh0, q0); q0 = MFMA(cnf[0][1], bh1, q0);
    q0 = MFMA(cnf[0][0], bl0, q0); q0 = MFMA(cnf[0][1], bl1, q0);
    q1 = MFMA(cnf[1][0], bh0, q1); q1 = MFMA(cnf[1][1], bh1, q1);
    q1 = MFMA(cnf[1][0], bl0, q1); q1 = MFMA(cnf[1][1], bl1, q1);
    q2 = MFMA(cnf[2][0], bh0, q2); q2 = MFMA(cnf[2][1], bh1, q2);
    q2 = MFMA(cnf[2][0], bl0, q2); q2 = MFMA(cnf[2][1], bl1, q2);
    f32x4 q[3] = {q0, q1, q2};

    // softmax over c; lane holds c = 16ct+4lg+r for row = lm (+16*g2)
    float e[3][4]; float psum = 0.f;
    #pragma unroll
    for (int ct = 0; ct < 3; ++ct)
      #pragma unroll
      for (int r = 0; r < 4; ++r) {
        int c = 16*ct + 4*lg + r;
        float ev = (c < C_) ? __expf(ALPHA_ * rn * q[ct][r]) : 0.f;
        e[ct][r] = ev; psum += ev;
      }
    psum += __shfl_xor(psum, 16);
    psum += __shfl_xor(psum, 32);
    float inva = 1.f / psum;
    float arn  = inva * rn;

    const int rowin = g2*16 + lm;        // row within 32-row unit
    #pragma unroll
    for (int ct = 0; ct < 3; ++ct)
      #pragma unroll
      for (int r = 0; r < 4; ++r) {
        sp[ct][r] = fmaf(q[ct][r]*rn, e[ct][r]*inva, sp[ct][r]);
        aw[(16*ct + 4*lg + r)*36 + rowin] = f2bf(e[ct][r] * arn);  // asg[c][row]
      }
    #pragma unroll
    for (int j = 0; j < 8; ++j) {
      xw[(     8*lg + j)*36 + rowin] = (unsigned short)bh0[j];     // xt[d][row]
      xw[(32 + 8*lg + j)*36 + rowin] = (unsigned short)bh1[j];
    }
  };

  const float* px = x + ((size_t)b*N_ + (size_t)nb*RPB_ + wid*128 + lm)*D_ + lg*8;

  float4 P0,P1,P2,P3, Q0,Q1,Q2,Q3;
  { const float* p = px;        P0=*(const float4*)p; P1=*(const float4*)(p+4); P2=*(const float4*)(p+32); P3=*(const float4*)(p+36); }
  { const float* p = px + 1024; Q0=*(const float4*)p; Q1=*(const float4*)(p+4); Q2=*(const float4*)(p+32); Q3=*(const float4*)(p+36); }

  #pragma unroll 2
  for (int u = 0; u < UNITS_; ++u) {
    float4 R0=P0,R1=P1,R2=P2,R3=P3, S0=Q0,S1=Q1,S2=Q2,S3=Q3;
    if (u < UNITS_-1) {
      const float* p = px + (size_t)(2*u+2)*1024;
      R0=*(const float4*)p; R1=*(const float4*)(p+4); R2=*(const float4*)(p+32); R3=*(const float4*)(p+36);
      const float* q = px + (size_t)(2*u+3)*1024;
      S0=*(const float4*)q; S1=*(const float4*)(q+4); S2=*(const float4*)(q+32); S3=*(const float4*)(q+36);
    }
    process(P0,P1,P2,P3, 0);
    process(Q0,Q1,Q2,Q3, 1);

    // ws GEMM over this 32-row unit (wave-local LDS, compiler-ordered)
    bf16x8 af0 = ld_frag(&aw[( 0 + lm)*36 + 8*lg]);
    bf16x8 af1 = ld_frag(&aw[(16 + lm)*36 + 8*lg]);
    bf16x8 af2 = ld_frag(&aw[(32 + lm)*36 + 8*lg]);
    #pragma unroll
    for (int nt = 0; nt < 4; ++nt) {
      bf16x8 xf = ld_frag(&xw[(16*nt + lm)*36 + 8*lg]);
      acc[0][nt] = MFMA(af0, xf, acc[0][nt]);
      acc[1][nt] = MFMA(af1, xf, acc[1][nt]);
      acc[2][nt] = MFMA(af2, xf, acc[2][nt]);
    }

    if (u < UNITS_-1) { P0=R0;P1=R1;P2=R2;P3=R3; Q0=S0;Q1=S1;Q2=S2;Q3=S3; }
  }

  // ---- epilogue ----
  if (t < CP_) spR[t] = 0.f;
  __syncthreads();                       // all waves done with sh.m (union reuse below)

  #pragma unroll
  for (int ct = 0; ct < 3; ++ct)
    #pragma unroll
    for (int r = 0; r < 4; ++r) {
      float v = sp[ct][r];
      v += __shfl_xor(v, 1); v += __shfl_xor(v, 2);
      v += __shfl_xor(v, 4); v += __shfl_xor(v, 8);
      if (lm == 0) atomicAdd(&spR[16*ct + 4*lg + r], v);
    }

  if (wid < 2) {
    #pragma unroll
    for (int ct = 0; ct < 3; ++ct)
      #pragma unroll
      for (int nt = 0; nt < 4; ++nt)
        #pragma unroll
        for (int r = 0; r < 4; ++r)
          sh.red[wid][(16*ct + 4*lg + r)*65 + 16*nt + lm] = acc[ct][nt][r];
  }
  __syncthreads();
  if (wid >= 2) {
    #pragma unroll
    for (int ct = 0; ct < 3; ++ct)
      #pragma unroll
      for (int nt = 0; nt < 4; ++nt)
        #pragma unroll
        for (int r = 0; r < 4; ++r)
          sh.red[wid-2][(16*ct + 4*lg + r)*65 + 16*nt + lm] += acc[ct][nt][r];
  }
  __syncthreads();

  if (NPART == NB_) {
    const size_t blk = blockIdx.x;
    for (int i = t; i < C_*D_; i += 256) {
      int c = i >> 6, d = i & 63;
      wsP[blk*(C_*D_) + i] = sh.red[0][c*65 + d] + sh.red[1][c*65 + d];
    }
    if (t < CP_) spP[blk*CP_ + t] = spR[t];
  } else {
    for (int i = t; i < C_*D_; i += 256) {
      int c = i >> 6, d = i & 63;
      atomicAdd(&wsP[(size_t)b*(C_*D_) + i], sh.red[0][c*65 + d] + sh.red[1][c*65 + d]);
    }
    if (t < CP_) atomicAdd(&spP[(size_t)b*CP_ + t], spR[t]);
  }
}

// ---------------------------------------------------------------------------
// Finalize: one block per batch; reduces NPART partials, projection, norms.
// ---------------------------------------------------------------------------
template<int NPART>
__global__ __launch_bounds__(256) void k_final(
    const float* __restrict__ cent, const float* __restrict__ wsP,
    const float* __restrict__ spP, float* __restrict__ out)
{
  const int b = blockIdx.x;
  const int t = threadIdx.x;
  __shared__ float nrmc[C_];
  __shared__ float spS[CP_];
  __shared__ float vl[C_][65];
  __shared__ float rc[C_];
  __shared__ float red4[4];

  if (t < C_) {
    float ss = 0.f;
    for (int d = 0; d < D_; ++d) { float v = cent[d*C_ + t]; ss = fmaf(v, v, ss); }
    nrmc[t] = rsqrtf(fmaxf(ss, 1e-24f));
  }
  if (t < CP_) {
    float s = 0.f;
    for (int k = 0; k < NPART; ++k) s += spP[((size_t)b*NPART + k)*CP_ + t];
    spS[t] = s;
  }
  __syncthreads();
  for (int i = t; i < C_*D_; i += 256) {
    int c = i >> 6, d = i & 63;
    float s = 0.f;
    for (int k = 0; k < NPART; ++k) s += wsP[((size_t)b*NPART + k)*(C_*D_) + i];
    float cn = cent[d*C_ + c] * nrmc[c];
    vl[c][d] = s - cn * spS[c];
  }
  __syncthreads();
  if (t < C_) {
    float ss = 0.f;
    for (int d = 0; d < D_; ++d) { float v = vl[t][d]; ss = fmaf(v, v, ss); }
    rc[t] = rsqrtf(fmaxf(ss, 1e-24f));
  }
  __syncthreads();
  float p = 0.f;
  for (int i = t; i < C_*D_; i += 256) {
    int c = i >> 6, d = i & 63;
    float v = vl[c][d] * rc[c];
    p = fmaf(v, v, p);
  }
  for (int off = 32; off; off >>= 1) p += __shfl_down(p, off);
  if ((t & 63) == 0) red4[t >> 6] = p;
  __syncthreads();
  float S = red4[0] + red4[1] + red4[2] + red4[3];
  float rg = rsqrtf(fmaxf(S, 1e-24f));
  for (int i = t; i < FG_*D_; i += 256) {
    int c = i >> 6, d = i & 63;
    out[(size_t)b*(FG_*D_) + i] = vl[c][d] * rc[c] * rg;
  }
}

extern "C" void kernel_launch(void* const* d_in, const int* in_sizes, int n_in,
                              void* d_out, int out_size, void* d_ws, size_t ws_size,
                              hipStream_t stream) {
  const float* x    = (const float*)d_in[0];
  const float* cent = (const float*)d_in[1];
  float* out = (float*)d_out;

  const size_t nblk = (size_t)B_ * NB_;                           // 1024
  const size_t need = (nblk*(C_*D_) + nblk*CP_) * sizeof(float);  // ~9.6 MB

  if (ws_size >= need) {
    float* wsP = (float*)d_ws;                          // [1024][2304]
    float* spP = wsP + nblk*(C_*D_);                    // [1024][48]
    k_accum<NB_><<<B_*NB_, 256, 0, stream>>>(x, cent, wsP, spP);
    k_final<NB_><<<B_, 256, 0, stream>>>(cent, wsP, spP, out);
  } else {                                              // atomic fallback
    float* wsA = (float*)d_ws;                          // [32][2304]
    float* spA = wsA + (size_t)B_*(C_*D_);              // [32][48]
    hipMemsetAsync(d_ws, 0, ((size_t)B_*(C_*D_) + (size_t)B_*CP_)*sizeof(float), stream);
    k_accum<1><<<B_*NB_, 256, 0, stream>>>(x, cent, wsA, spA);
    k_final<1><<<B_, 256, 0, stream>>>(cent, wsA, spA, out);
  }
}

// Round 6
// 56.154 us; speedup vs baseline: 1.9619x; 1.9619x over previous
//
#include <hip/hip_runtime.h>
#include <hip/hip_bf16.h>

#define B_     32
#define N_     16384
#define D_     64
#define C_     36
#define CP_    48     // padded cluster count (3 x 16 MFMA tiles)
#define FG_    32
#define ALPHA_ 10.0f
#define NB_    32     // n-blocks per batch -> grid 1024 = 4 blocks/CU exactly
#define RPB_   (N_/NB_)   // 512 rows per block
#define UNITS_ 4          // per wave: 4 units x 32 rows = 128 rows

typedef __attribute__((ext_vector_type(8))) short bf16x8;
typedef __attribute__((ext_vector_type(4))) short bf16x4;
typedef __attribute__((ext_vector_type(4))) float f32x4;

#define MFMA(a,b,c) __builtin_amdgcn_mfma_f32_16x16x32_bf16(a,b,c,0,0,0)

__device__ __forceinline__ unsigned short f2bf(float f){
  unsigned u = __float_as_uint(f);
  unsigned r = u + 0x7fffu + ((u >> 16) & 1u);   // RNE; inputs finite
  return (unsigned short)(r >> 16);
}
__device__ __forceinline__ float bf2f(unsigned short u){
  return __uint_as_float((unsigned)u << 16);
}

// v -> hi bf16 (slot J of H) + residual lo bf16 (slot J of L)
#define CVT1(v, H, L, J) { unsigned short hb_ = f2bf(v); (H)[J] = (short)hb_; \
  (L)[J] = (short)f2bf((v) - bf2f(hb_)); }

__device__ __forceinline__ bf16x8 ld_frag(const unsigned short* p){
  bf16x4 a = *(const bf16x4*)p;
  bf16x4 b = *(const bf16x4*)(p + 4);
  return __builtin_shufflevector(a, b, 0,1,2,3,4,5,6,7);
}

// ---------------------------------------------------------------------------
// Fused kernel. grid = 1024 (32 batches x 32 n-blocks), block = 256 = 4 waves.
// Wave owns 128 rows: 4 units of 32 rows (2 groups of 16).
// Rolling depth-1-group prefetch (8 live float4 -> no spill; round-2 proven).
// Per 16-row group: row norm -> bf16 hi/lo frags -> cos MFMA -> softmax ->
//   asg/x^T staged to LDS (transposed layout, pitch 36).
// Per unit: ws MFMA with A(asg),B(x^T) fragments via b64 LDS reads.
// NPART==NB_: non-atomic per-block partials; NPART==1: atomic fallback.
// ---------------------------------------------------------------------------
template<int NPART>
__global__ __launch_bounds__(256, 2) void k_accum(
    const float* __restrict__ x, const float* __restrict__ cent,
    float* __restrict__ wsP, float* __restrict__ spP)
{
  const int t   = threadIdx.x;
  const int wid = t >> 6;
  const int l   = t & 63;
  const int lm  = l & 15;
  const int lg  = l >> 4;
  const int b   = blockIdx.x >> 5;
  const int nb  = blockIdx.x & 31;

  __shared__ float nrmc[C_];
  __shared__ float spR[CP_];
  __shared__ __align__(16) union {
    struct { unsigned short asg[4][CP_*36]; unsigned short xt[4][64*36]; } m; // 32256 B
    float red[2][CP_*65];                                                     // 24960 B
  } sh;

  if (t < C_) {
    float ss = 0.f;
    for (int d = 0; d < D_; ++d) { float v = cent[d*C_ + t]; ss = fmaf(v, v, ss); }
    nrmc[t] = rsqrtf(fmaxf(ss, 1e-24f));
  }
  __syncthreads();

  // normalized-centroid A-fragments: A[m=c][k=d], c = 16*ct+lm, d = 32*s+8*lg+j
  bf16x8 cnf[3][2];
  #pragma unroll
  for (int ct = 0; ct < 3; ++ct) {
    #pragma unroll
    for (int s = 0; s < 2; ++s) {
      bf16x8 f;
      #pragma unroll
      for (int j = 0; j < 8; ++j) {
        int d = 32*s + 8*lg + j;
        int c = 16*ct + lm;
        float v = (c < C_) ? cent[d*C_ + c] * nrmc[c] : 0.f;
        f[j] = (short)f2bf(v);
      }
      cnf[ct][s] = f;
    }
  }

  f32x4 acc[3][4];
  #pragma unroll
  for (int ct = 0; ct < 3; ++ct)
    #pragma unroll
    for (int nt = 0; nt < 4; ++nt) acc[ct][nt] = (f32x4){0.f,0.f,0.f,0.f};
  float sp[3][4];
  #pragma unroll
  for (int ct = 0; ct < 3; ++ct)
    #pragma unroll
    for (int r = 0; r < 4; ++r) sp[ct][r] = 0.f;

  unsigned short* aw = sh.m.asg[wid];
  unsigned short* xw = sh.m.xt[wid];

  // per-16-row-group staging: lane holds row lm, float cols {8lg..+7, 32+8lg..+7}
  auto process = [&](float4 c0, float4 c1, float4 c2, float4 c3, int g2) {
    float ss = 0.f;
    ss = fmaf(c0.x,c0.x,ss); ss = fmaf(c0.y,c0.y,ss); ss = fmaf(c0.z,c0.z,ss); ss = fmaf(c0.w,c0.w,ss);
    ss = fmaf(c1.x,c1.x,ss); ss = fmaf(c1.y,c1.y,ss); ss = fmaf(c1.z,c1.z,ss); ss = fmaf(c1.w,c1.w,ss);
    ss = fmaf(c2.x,c2.x,ss); ss = fmaf(c2.y,c2.y,ss); ss = fmaf(c2.z,c2.z,ss); ss = fmaf(c2.w,c2.w,ss);
    ss = fmaf(c3.x,c3.x,ss); ss = fmaf(c3.y,c3.y,ss); ss = fmaf(c3.z,c3.z,ss); ss = fmaf(c3.w,c3.w,ss);
    ss += __shfl_xor(ss, 16);
    ss += __shfl_xor(ss, 32);
    float rn = rsqrtf(fmaxf(ss, 1e-24f));

    bf16x8 bh0, bl0, bh1, bl1;
    CVT1(c0.x,bh0,bl0,0) CVT1(c0.y,bh0,bl0,1) CVT1(c0.z,bh0,bl0,2) CVT1(c0.w,bh0,bl0,3)
    CVT1(c1.x,bh0,bl0,4) CVT1(c1.y,bh0,bl0,5) CVT1(c1.z,bh0,bl0,6) CVT1(c1.w,bh0,bl0,7)
    CVT1(c2.x,bh1,bl1,0) CVT1(c2.y,bh1,bl1,1) CVT1(c2.z,bh1,bl1,2) CVT1(c2.w,bh1,bl1,3)
    CVT1(c3.x,bh1,bl1,4) CVT1(c3.y,bh1,bl1,5) CVT1(c3.z,bh1,bl1,6) CVT1(c3.w,bh1,bl1,7)

    // cos GEMM: D[m=c][n=row] = cn . x (raw x; rn applied after)
    f32x4 q0 = (f32x4){0,0,0,0}, q1 = (f32x4){0,0,0,0}, q2 = (f32x4){0,0,0,0};
    q0 = MFMA(cnf[0][0], bh0, q0); q0 = MFMA(cnf[0][1], bh1, q0);
    q0 = MFMA(cnf[0][0], bl0, q0); q0 = MFMA(cnf[0][1], bl1, q0);
    q1 = MFMA(cnf[1][0], bh0, q1); q1 = MFMA(cnf[1][1], bh1, q1);
    q1 = MFMA(cnf[1][0], bl0, q1); q1 = MFMA(cnf[1][1], bl1, q1);
    q2 = MFMA(cnf[2][0], bh0, q2); q2 = MFMA(cnf[2][1], bh1, q2);
    q2 = MFMA(cnf[2][0], bl0, q2); q2 = MFMA(cnf[2][1], bl1, q2);
    f32x4 q[3] = {q0, q1, q2};

    // softmax over c; lane holds c = 16ct+4lg+r for row = lm (+16*g2)
    float e[3][4]; float psum = 0.f;
    #pragma unroll
    for (int ct = 0; ct < 3; ++ct)
      #pragma unroll
      for (int r = 0; r < 4; ++r) {
        int c = 16*ct + 4*lg + r;
        float ev = (c < C_) ? __expf(ALPHA_ * rn * q[ct][r]) : 0.f;
        e[ct][r] = ev; psum += ev;
      }
    psum += __shfl_xor(psum, 16);
    psum += __shfl_xor(psum, 32);
    float inva = 1.f / psum;
    float arn  = inva * rn;

    const int rowin = g2*16 + lm;        // row within 32-row unit
    #pragma unroll
    for (int ct = 0; ct < 3; ++ct)
      #pragma unroll
      for (int r = 0; r < 4; ++r) {
        sp[ct][r] = fmaf(q[ct][r]*rn, e[ct][r]*inva, sp[ct][r]);
        aw[(16*ct + 4*lg + r)*36 + rowin] = f2bf(e[ct][r] * arn);  // asg[c][row]
      }
    #pragma unroll
    for (int j = 0; j < 8; ++j) {
      xw[(     8*lg + j)*36 + rowin] = (unsigned short)bh0[j];     // xt[d][row]
      xw[(32 + 8*lg + j)*36 + rowin] = (unsigned short)bh1[j];
    }
  };

  const float* px = x + ((size_t)b*N_ + (size_t)nb*RPB_ + wid*128 + lm)*D_ + lg*8;

  float4 A0,A1,A2,A3;
  { const float* p = px; A0=*(const float4*)p; A1=*(const float4*)(p+4); A2=*(const float4*)(p+32); A3=*(const float4*)(p+36); }

  for (int u = 0; u < UNITS_; ++u) {
    #pragma unroll
    for (int g2 = 0; g2 < 2; ++g2) {
      const int g = 2*u + g2;
      float4 c0=A0, c1=A1, c2=A2, c3=A3;
      if (g < 2*UNITS_-1) {
        const float* p = px + (size_t)(g+1)*1024;   // next 16-row group
        A0=*(const float4*)p; A1=*(const float4*)(p+4); A2=*(const float4*)(p+32); A3=*(const float4*)(p+36);
      }
      process(c0,c1,c2,c3, g2);
    }

    // ws GEMM over this 32-row unit (wave-local LDS, compiler-ordered)
    bf16x8 af0 = ld_frag(&aw[( 0 + lm)*36 + 8*lg]);
    bf16x8 af1 = ld_frag(&aw[(16 + lm)*36 + 8*lg]);
    bf16x8 af2 = ld_frag(&aw[(32 + lm)*36 + 8*lg]);
    #pragma unroll
    for (int nt = 0; nt < 4; ++nt) {
      bf16x8 xf = ld_frag(&xw[(16*nt + lm)*36 + 8*lg]);
      acc[0][nt] = MFMA(af0, xf, acc[0][nt]);
      acc[1][nt] = MFMA(af1, xf, acc[1][nt]);
      acc[2][nt] = MFMA(af2, xf, acc[2][nt]);
    }
  }

  // ---- epilogue ----
  if (t < CP_) spR[t] = 0.f;
  __syncthreads();                       // all waves done with sh.m (union reuse below)

  #pragma unroll
  for (int ct = 0; ct < 3; ++ct)
    #pragma unroll
    for (int r = 0; r < 4; ++r) {
      float v = sp[ct][r];
      v += __shfl_xor(v, 1); v += __shfl_xor(v, 2);
      v += __shfl_xor(v, 4); v += __shfl_xor(v, 8);
      if (lm == 0) atomicAdd(&spR[16*ct + 4*lg + r], v);
    }

  if (wid < 2) {
    #pragma unroll
    for (int ct = 0; ct < 3; ++ct)
      #pragma unroll
      for (int nt = 0; nt < 4; ++nt)
        #pragma unroll
        for (int r = 0; r < 4; ++r)
          sh.red[wid][(16*ct + 4*lg + r)*65 + 16*nt + lm] = acc[ct][nt][r];
  }
  __syncthreads();
  if (wid >= 2) {
    #pragma unroll
    for (int ct = 0; ct < 3; ++ct)
      #pragma unroll
      for (int nt = 0; nt < 4; ++nt)
        #pragma unroll
        for (int r = 0; r < 4; ++r)
          sh.red[wid-2][(16*ct + 4*lg + r)*65 + 16*nt + lm] += acc[ct][nt][r];
  }
  __syncthreads();

  if (NPART == NB_) {
    const size_t blk = blockIdx.x;
    for (int i = t; i < C_*D_; i += 256) {
      int c = i >> 6, d = i & 63;
      wsP[blk*(C_*D_) + i] = sh.red[0][c*65 + d] + sh.red[1][c*65 + d];
    }
    if (t < CP_) spP[blk*CP_ + t] = spR[t];
  } else {
    for (int i = t; i < C_*D_; i += 256) {
      int c = i >> 6, d = i & 63;
      atomicAdd(&wsP[(size_t)b*(C_*D_) + i], sh.red[0][c*65 + d] + sh.red[1][c*65 + d]);
    }
    if (t < CP_) atomicAdd(&spP[(size_t)b*CP_ + t], spR[t]);
  }
}

// ---------------------------------------------------------------------------
// Finalize: one block (1024 threads) per batch; reduces NPART partials,
// projection, per-cluster norm, global norm, write fg.
// ---------------------------------------------------------------------------
template<int NPART>
__global__ __launch_bounds__(1024) void k_final(
    const float* __restrict__ cent, const float* __restrict__ wsP,
    const float* __restrict__ spP, float* __restrict__ out)
{
  const int b = blockIdx.x;
  const int t = threadIdx.x;
  __shared__ float nrmc[C_];
  __shared__ float spS[CP_];
  __shared__ float vl[C_][65];
  __shared__ float rc[C_];
  __shared__ float redw[16];

  if (t < C_) {
    float ss = 0.f;
    for (int d = 0; d < D_; ++d) { float v = cent[d*C_ + t]; ss = fmaf(v, v, ss); }
    nrmc[t] = rsqrtf(fmaxf(ss, 1e-24f));
  }
  if (t >= 64 && t < 64 + CP_) {
    int c = t - 64;
    float s = 0.f;
    #pragma unroll 4
    for (int k = 0; k < NPART; ++k) s += spP[((size_t)b*NPART + k)*CP_ + c];
    spS[c] = s;
  }
  __syncthreads();
  for (int i = t; i < C_*D_; i += 1024) {
    float s = 0.f;
    #pragma unroll 4
    for (int k = 0; k < NPART; ++k) s += wsP[((size_t)b*NPART + k)*(C_*D_) + i];
    int c = i >> 6, d = i & 63;
    float cn = cent[d*C_ + c] * nrmc[c];
    vl[c][d] = s - cn * spS[c];
  }
  __syncthreads();
  if (t < C_) {
    float ss = 0.f;
    for (int d = 0; d < D_; ++d) { float v = vl[t][d]; ss = fmaf(v, v, ss); }
    rc[t] = rsqrtf(fmaxf(ss, 1e-24f));
  }
  __syncthreads();
  float p = 0.f;
  for (int i = t; i < C_*D_; i += 1024) {
    int c = i >> 6, d = i & 63;
    float v = vl[c][d] * rc[c];
    p = fmaf(v, v, p);
  }
  for (int off = 32; off; off >>= 1) p += __shfl_down(p, off);
  if ((t & 63) == 0) redw[t >> 6] = p;
  __syncthreads();
  float S = 0.f;
  #pragma unroll
  for (int w = 0; w < 16; ++w) S += redw[w];
  float rg = rsqrtf(fmaxf(S, 1e-24f));
  for (int i = t; i < FG_*D_; i += 1024) {
    int c = i >> 6, d = i & 63;
    out[(size_t)b*(FG_*D_) + i] = vl[c][d] * rc[c] * rg;
  }
}

extern "C" void kernel_launch(void* const* d_in, const int* in_sizes, int n_in,
                              void* d_out, int out_size, void* d_ws, size_t ws_size,
                              hipStream_t stream) {
  const float* x    = (const float*)d_in[0];
  const float* cent = (const float*)d_in[1];
  float* out = (float*)d_out;

  const size_t nblk = (size_t)B_ * NB_;                           // 1024
  const size_t need = (nblk*(C_*D_) + nblk*CP_) * sizeof(float);  // ~9.6 MB

  if (ws_size >= need) {
    float* wsP = (float*)d_ws;                          // [1024][2304]
    float* spP = wsP + nblk*(C_*D_);                    // [1024][48]
    k_accum<NB_><<<B_*NB_, 256, 0, stream>>>(x, cent, wsP, spP);
    k_final<NB_><<<B_, 1024, 0, stream>>>(cent, wsP, spP, out);
  } else {                                              // atomic fallback
    float* wsA = (float*)d_ws;                          // [32][2304]
    float* spA = wsA + (size_t)B_*(C_*D_);              // [32][48]
    hipMemsetAsync(d_ws, 0, ((size_t)B_*(C_*D_) + (size_t)B_*CP_)*sizeof(float), stream);
    k_accum<1><<<B_*NB_, 256, 0, stream>>>(x, cent, wsA, spA);
    k_final<1><<<B_, 1024, 0, stream>>>(cent, wsA, spA, out);
  }
}

// Round 7
// 51.938 us; speedup vs baseline: 2.1212x; 1.0812x over previous
//
#include <hip/hip_runtime.h>
#include <hip/hip_bf16.h>

#define B_     32
#define N_     16384
#define D_     64
#define C_     36
#define CP_    48     // padded cluster count (3 x 16 MFMA tiles)
#define FG_    32
#define ALPHA_ 10.0f
#define NB_    32     // n-blocks per batch -> grid 1024 = 4 blocks/CU exactly
#define RPB_   (N_/NB_)   // 512 rows per block
#define UNITS_ 4          // per wave: 4 units x 32 rows = 128 rows

typedef __attribute__((ext_vector_type(8))) short bf16x8;
typedef __attribute__((ext_vector_type(4))) short bf16x4;
typedef __attribute__((ext_vector_type(4))) float f32x4;

#define MFMA(a,b,c) __builtin_amdgcn_mfma_f32_16x16x32_bf16(a,b,c,0,0,0)

// float -> bf16 bits via native conversion (v_cvt_pk_bf16_f32, RNE on gfx950).
__device__ __forceinline__ short bfbits(float v){
  __bf16 h = (__bf16)v;
  return __builtin_bit_cast(short, h);
}
__device__ __forceinline__ float bfval(short u){
  return __uint_as_float(((unsigned)(unsigned short)u) << 16);
}

// v -> hi bf16 (slot J of H) + residual lo bf16 (slot J of L)
#define CVT1(v, H, L, J) { short hb_ = bfbits(v); (H)[J] = hb_; \
  (L)[J] = bfbits((v) - bfval(hb_)); }

__device__ __forceinline__ bf16x8 ld_frag(const unsigned short* p){
  bf16x4 a = *(const bf16x4*)p;
  bf16x4 b = *(const bf16x4*)(p + 4);
  return __builtin_shufflevector(a, b, 0,1,2,3,4,5,6,7);
}

// ---------------------------------------------------------------------------
// Fused kernel. grid = 1024 (32 batches x 32 n-blocks), block = 256 = 4 waves.
// Wave owns 128 rows: 4 units of 32 rows (2 groups of 16).
// Rolling depth-1-group prefetch (8 live float4 -> no spill; proven).
// Per 16-row group: row norm -> bf16 hi/lo frags (native cvt) -> cos MFMA ->
//   softmax -> asg/x^T staged to LDS (transposed layout, pitch 36).
// Per unit: ws MFMA with A(asg),B(x^T) fragments via b64 LDS reads.
// NPART==NB_: non-atomic per-block partials; NPART==1: atomic fallback.
// ---------------------------------------------------------------------------
template<int NPART>
__global__ __launch_bounds__(256, 2) void k_accum(
    const float* __restrict__ x, const float* __restrict__ cent,
    float* __restrict__ wsP, float* __restrict__ spP)
{
  const int t   = threadIdx.x;
  const int wid = t >> 6;
  const int l   = t & 63;
  const int lm  = l & 15;
  const int lg  = l >> 4;
  const int b   = blockIdx.x >> 5;
  const int nb  = blockIdx.x & 31;

  __shared__ float nrmc[C_];
  __shared__ float spR[CP_];
  __shared__ __align__(16) union {
    struct { unsigned short asg[4][CP_*36]; unsigned short xt[4][64*36]; } m; // 32256 B
    float red[2][CP_*65];                                                     // 24960 B
  } sh;

  if (t < C_) {
    float ss = 0.f;
    for (int d = 0; d < D_; ++d) { float v = cent[d*C_ + t]; ss = fmaf(v, v, ss); }
    nrmc[t] = rsqrtf(fmaxf(ss, 1e-24f));
  }
  __syncthreads();

  // normalized-centroid A-fragments: A[m=c][k=d], c = 16*ct+lm, d = 32*s+8*lg+j
  bf16x8 cnf[3][2];
  #pragma unroll
  for (int ct = 0; ct < 3; ++ct) {
    #pragma unroll
    for (int s = 0; s < 2; ++s) {
      bf16x8 f;
      #pragma unroll
      for (int j = 0; j < 8; ++j) {
        int d = 32*s + 8*lg + j;
        int c = 16*ct + lm;
        float v = (c < C_) ? cent[d*C_ + c] * nrmc[c] : 0.f;
        f[j] = bfbits(v);
      }
      cnf[ct][s] = f;
    }
  }

  f32x4 acc[3][4];
  #pragma unroll
  for (int ct = 0; ct < 3; ++ct)
    #pragma unroll
    for (int nt = 0; nt < 4; ++nt) acc[ct][nt] = (f32x4){0.f,0.f,0.f,0.f};
  float sp[3][4];
  #pragma unroll
  for (int ct = 0; ct < 3; ++ct)
    #pragma unroll
    for (int r = 0; r < 4; ++r) sp[ct][r] = 0.f;

  unsigned short* aw = sh.m.asg[wid];
  unsigned short* xw = sh.m.xt[wid];

  // per-16-row-group staging: lane holds row lm, float cols {8lg..+7, 32+8lg..+7}
  auto process = [&](float4 c0, float4 c1, float4 c2, float4 c3, int g2) {
    float ss = 0.f;
    ss = fmaf(c0.x,c0.x,ss); ss = fmaf(c0.y,c0.y,ss); ss = fmaf(c0.z,c0.z,ss); ss = fmaf(c0.w,c0.w,ss);
    ss = fmaf(c1.x,c1.x,ss); ss = fmaf(c1.y,c1.y,ss); ss = fmaf(c1.z,c1.z,ss); ss = fmaf(c1.w,c1.w,ss);
    ss = fmaf(c2.x,c2.x,ss); ss = fmaf(c2.y,c2.y,ss); ss = fmaf(c2.z,c2.z,ss); ss = fmaf(c2.w,c2.w,ss);
    ss = fmaf(c3.x,c3.x,ss); ss = fmaf(c3.y,c3.y,ss); ss = fmaf(c3.z,c3.z,ss); ss = fmaf(c3.w,c3.w,ss);
    ss += __shfl_xor(ss, 16);
    ss += __shfl_xor(ss, 32);
    float rn = rsqrtf(fmaxf(ss, 1e-24f));

    bf16x8 bh0, bl0, bh1, bl1;
    CVT1(c0.x,bh0,bl0,0) CVT1(c0.y,bh0,bl0,1) CVT1(c0.z,bh0,bl0,2) CVT1(c0.w,bh0,bl0,3)
    CVT1(c1.x,bh0,bl0,4) CVT1(c1.y,bh0,bl0,5) CVT1(c1.z,bh0,bl0,6) CVT1(c1.w,bh0,bl0,7)
    CVT1(c2.x,bh1,bl1,0) CVT1(c2.y,bh1,bl1,1) CVT1(c2.z,bh1,bl1,2) CVT1(c2.w,bh1,bl1,3)
    CVT1(c3.x,bh1,bl1,4) CVT1(c3.y,bh1,bl1,5) CVT1(c3.z,bh1,bl1,6) CVT1(c3.w,bh1,bl1,7)

    // cos GEMM: D[m=c][n=row] = cn . x (raw x; rn applied after)
    f32x4 q0 = (f32x4){0,0,0,0}, q1 = (f32x4){0,0,0,0}, q2 = (f32x4){0,0,0,0};
    q0 = MFMA(cnf[0][0], bh0, q0); q0 = MFMA(cnf[0][1], bh1, q0);
    q0 = MFMA(cnf[0][0], bl0, q0); q0 = MFMA(cnf[0][1], bl1, q0);
    q1 = MFMA(cnf[1][0], bh0, q1); q1 = MFMA(cnf[1][1], bh1, q1);
    q1 = MFMA(cnf[1][0], bl0, q1); q1 = MFMA(cnf[1][1], bl1, q1);
    q2 = MFMA(cnf[2][0], bh0, q2); q2 = MFMA(cnf[2][1], bh1, q2);
    q2 = MFMA(cnf[2][0], bl0, q2); q2 = MFMA(cnf[2][1], bl1, q2);
    f32x4 q[3] = {q0, q1, q2};

    // softmax over c; lane holds c = 16ct+4lg+r for row = lm (+16*g2)
    float e[3][4]; float psum = 0.f;
    #pragma unroll
    for (int ct = 0; ct < 3; ++ct)
      #pragma unroll
      for (int r = 0; r < 4; ++r) {
        int c = 16*ct + 4*lg + r;
        float ev = (c < C_) ? __expf(ALPHA_ * rn * q[ct][r]) : 0.f;
        e[ct][r] = ev; psum += ev;
      }
    psum += __shfl_xor(psum, 16);
    psum += __shfl_xor(psum, 32);
    float inva = 1.f / psum;
    float arn  = inva * rn;

    const int rowin = g2*16 + lm;        // row within 32-row unit
    #pragma unroll
    for (int ct = 0; ct < 3; ++ct)
      #pragma unroll
      for (int r = 0; r < 4; ++r) {
        sp[ct][r] = fmaf(q[ct][r]*rn, e[ct][r]*inva, sp[ct][r]);
        aw[(16*ct + 4*lg + r)*36 + rowin] = (unsigned short)bfbits(e[ct][r] * arn);
      }
    #pragma unroll
    for (int j = 0; j < 8; ++j) {
      xw[(     8*lg + j)*36 + rowin] = (unsigned short)bh0[j];     // xt[d][row]
      xw[(32 + 8*lg + j)*36 + rowin] = (unsigned short)bh1[j];
    }
  };

  const float* px = x + ((size_t)b*N_ + (size_t)nb*RPB_ + wid*128 + lm)*D_ + lg*8;

  float4 A0,A1,A2,A3;
  { const float* p = px; A0=*(const float4*)p; A1=*(const float4*)(p+4); A2=*(const float4*)(p+32); A3=*(const float4*)(p+36); }

  for (int u = 0; u < UNITS_; ++u) {
    #pragma unroll
    for (int g2 = 0; g2 < 2; ++g2) {
      const int g = 2*u + g2;
      float4 c0=A0, c1=A1, c2=A2, c3=A3;
      if (g < 2*UNITS_-1) {
        const float* p = px + (size_t)(g+1)*1024;   // next 16-row group
        A0=*(const float4*)p; A1=*(const float4*)(p+4); A2=*(const float4*)(p+32); A3=*(const float4*)(p+36);
      }
      process(c0,c1,c2,c3, g2);
    }

    // ws GEMM over this 32-row unit (wave-local LDS, compiler-ordered)
    bf16x8 af0 = ld_frag(&aw[( 0 + lm)*36 + 8*lg]);
    bf16x8 af1 = ld_frag(&aw[(16 + lm)*36 + 8*lg]);
    bf16x8 af2 = ld_frag(&aw[(32 + lm)*36 + 8*lg]);
    #pragma unroll
    for (int nt = 0; nt < 4; ++nt) {
      bf16x8 xf = ld_frag(&xw[(16*nt + lm)*36 + 8*lg]);
      acc[0][nt] = MFMA(af0, xf, acc[0][nt]);
      acc[1][nt] = MFMA(af1, xf, acc[1][nt]);
      acc[2][nt] = MFMA(af2, xf, acc[2][nt]);
    }
  }

  // ---- epilogue ----
  if (t < CP_) spR[t] = 0.f;
  __syncthreads();                       // all waves done with sh.m (union reuse below)

  #pragma unroll
  for (int ct = 0; ct < 3; ++ct)
    #pragma unroll
    for (int r = 0; r < 4; ++r) {
      float v = sp[ct][r];
      v += __shfl_xor(v, 1); v += __shfl_xor(v, 2);
      v += __shfl_xor(v, 4); v += __shfl_xor(v, 8);
      if (lm == 0) atomicAdd(&spR[16*ct + 4*lg + r], v);
    }

  if (wid < 2) {
    #pragma unroll
    for (int ct = 0; ct < 3; ++ct)
      #pragma unroll
      for (int nt = 0; nt < 4; ++nt)
        #pragma unroll
        for (int r = 0; r < 4; ++r)
          sh.red[wid][(16*ct + 4*lg + r)*65 + 16*nt + lm] = acc[ct][nt][r];
  }
  __syncthreads();
  if (wid >= 2) {
    #pragma unroll
    for (int ct = 0; ct < 3; ++ct)
      #pragma unroll
      for (int nt = 0; nt < 4; ++nt)
        #pragma unroll
        for (int r = 0; r < 4; ++r)
          sh.red[wid-2][(16*ct + 4*lg + r)*65 + 16*nt + lm] += acc[ct][nt][r];
  }
  __syncthreads();

  if (NPART == NB_) {
    const size_t blk = blockIdx.x;
    for (int i = t; i < C_*D_; i += 256) {
      int c = i >> 6, d = i & 63;
      wsP[blk*(C_*D_) + i] = sh.red[0][c*65 + d] + sh.red[1][c*65 + d];
    }
    if (t < CP_) spP[blk*CP_ + t] = spR[t];
  } else {
    for (int i = t; i < C_*D_; i += 256) {
      int c = i >> 6, d = i & 63;
      atomicAdd(&wsP[(size_t)b*(C_*D_) + i], sh.red[0][c*65 + d] + sh.red[1][c*65 + d]);
    }
    if (t < CP_) atomicAdd(&spP[(size_t)b*CP_ + t], spR[t]);
  }
}

// ---------------------------------------------------------------------------
// Reduce stage 1: grid = B_*C_ (1152 blocks), one wave each.
// Reduces NPART partials for one (b,c), applies projection, computes
// per-cluster sum-of-squares. Spreads partial traffic over all CUs.
// ---------------------------------------------------------------------------
template<int NPART>
__global__ __launch_bounds__(64) void k_red1(
    const float* __restrict__ cent, const float* __restrict__ wsP,
    const float* __restrict__ spP, float* __restrict__ vl,
    float* __restrict__ css)
{
  const int bc = blockIdx.x;
  const int b  = bc / C_;
  const int c  = bc - b*C_;
  const int d  = threadIdx.x;

  // normalized centroid component cn[d][c]
  float cv = cent[d*C_ + c];
  float cs = cv*cv;
  #pragma unroll
  for (int off = 32; off; off >>= 1) cs += __shfl_xor(cs, off);
  float cn = cv * rsqrtf(fmaxf(cs, 1e-24f));

  // self-product sum over partials
  float spv;
  if (NPART > 1) {
    float v = (d < NPART) ? spP[((size_t)b*NPART + d)*CP_ + c] : 0.f;
    #pragma unroll
    for (int off = 32; off; off >>= 1) v += __shfl_xor(v, off);
    spv = v;
  } else {
    spv = spP[(size_t)b*CP_ + c];
  }

  // weighted-sum over partials (coalesced across d)
  float s = 0.f;
  #pragma unroll 4
  for (int k = 0; k < NPART; ++k)
    s += wsP[((size_t)b*NPART + k)*(C_*D_) + c*D_ + d];

  float v = s - cn * spv;
  float vs = v*v;
  #pragma unroll
  for (int off = 32; off; off >>= 1) vs += __shfl_xor(vs, off);

  vl[(size_t)bc*D_ + d] = v;
  if (d == 0) css[bc] = vs;
}

// ---------------------------------------------------------------------------
// Reduce stage 2: one block per batch; per-cluster + global norm, write fg.
// ---------------------------------------------------------------------------
__global__ __launch_bounds__(256) void k_fin2(
    const float* __restrict__ vl, const float* __restrict__ css,
    float* __restrict__ out)
{
  const int b = blockIdx.x;
  const int t = threadIdx.x;
  __shared__ float rc[C_];
  __shared__ float rgs;

  if (t < C_) rc[t] = rsqrtf(fmaxf(css[b*C_ + t], 1e-24f));
  __syncthreads();
  if (t == 0) {
    float S = 0.f;
    for (int c = 0; c < C_; ++c) {
      float csv = css[b*C_ + c];
      S = fmaf(csv, rc[c]*rc[c], S);
    }
    rgs = rsqrtf(fmaxf(S, 1e-24f));
  }
  __syncthreads();
  float rg = rgs;
  for (int i = t; i < FG_*D_; i += 256) {
    int c = i >> 6, d = i & 63;
    out[(size_t)b*(FG_*D_) + i] = vl[(size_t)(b*C_ + c)*D_ + d] * rc[c] * rg;
  }
}

extern "C" void kernel_launch(void* const* d_in, const int* in_sizes, int n_in,
                              void* d_out, int out_size, void* d_ws, size_t ws_size,
                              hipStream_t stream) {
  const float* x    = (const float*)d_in[0];
  const float* cent = (const float*)d_in[1];
  float* out = (float*)d_out;

  const size_t nblk = (size_t)B_ * NB_;                            // 1024
  const size_t wsN  = nblk*(C_*D_);                                // partial ws
  const size_t spN  = nblk*CP_;                                    // partial sp
  const size_t vlN  = (size_t)B_*C_*D_;
  const size_t csN  = (size_t)B_*C_;
  const size_t need = (wsN + spN + vlN + csN) * sizeof(float);     // ~9.9 MB

  if (ws_size >= need) {
    float* wsP = (float*)d_ws;
    float* spP = wsP + wsN;
    float* vl  = spP + spN;
    float* css = vl  + vlN;
    k_accum<NB_><<<B_*NB_, 256, 0, stream>>>(x, cent, wsP, spP);
    k_red1<NB_><<<B_*C_, 64, 0, stream>>>(cent, wsP, spP, vl, css);
    k_fin2<<<B_, 256, 0, stream>>>(vl, css, out);
  } else {                                              // atomic fallback
    float* wsA = (float*)d_ws;                          // [32][2304]
    float* spA = wsA + (size_t)B_*(C_*D_);              // [32][48]
    float* vl  = spA + (size_t)B_*CP_;
    float* css = vl  + vlN;
    hipMemsetAsync(d_ws, 0, ((size_t)B_*(C_*D_) + (size_t)B_*CP_)*sizeof(float), stream);
    k_accum<1><<<B_*NB_, 256, 0, stream>>>(x, cent, wsA, spA);
    k_red1<1><<<B_*C_, 64, 0, stream>>>(cent, wsA, spA, vl, css);
    k_fin2<<<B_, 256, 0, stream>>>(vl, css, out);
  }
}

// Round 8
// 40.872 us; speedup vs baseline: 2.6955x; 1.2707x over previous
//
#include <hip/hip_runtime.h>
#include <hip/hip_bf16.h>

#define B_     32
#define N_     16384
#define D_     64
#define C_     36
#define CP_    48     // padded cluster count (3 x 16 MFMA tiles)
#define FG_    32
#define ALPHA_ 10.0f
#define NB_    32     // n-blocks per batch -> grid 1024 = 4 blocks/CU exactly
#define RPB_   (N_/NB_)   // 512 rows per block
#define UNITS_ 4          // per wave: 4 units x 32 rows = 128 rows

typedef __attribute__((ext_vector_type(8))) short bf16x8;
typedef __attribute__((ext_vector_type(4))) short bf16x4;
typedef __attribute__((ext_vector_type(4))) float f32x4;

#define MFMA(a,b,c) __builtin_amdgcn_mfma_f32_16x16x32_bf16(a,b,c,0,0,0)

// float -> bf16 bits via native conversion (v_cvt_pk_bf16_f32, RNE on gfx950).
__device__ __forceinline__ short bfbits(float v){
  __bf16 h = (__bf16)v;
  return __builtin_bit_cast(short, h);
}
__device__ __forceinline__ float bfval(short u){
  return __uint_as_float(((unsigned)(unsigned short)u) << 16);
}

// v -> hi bf16 (slot J of H) + residual lo bf16 (slot J of L)
#define CVT1(v, H, L, J) { short hb_ = bfbits(v); (H)[J] = hb_; \
  (L)[J] = bfbits((v) - bfval(hb_)); }

__device__ __forceinline__ bf16x8 ld_frag(const unsigned short* p){
  bf16x4 a = *(const bf16x4*)p;
  bf16x4 b = *(const bf16x4*)(p + 4);
  return __builtin_shufflevector(a, b, 0,1,2,3,4,5,6,7);
}

// ---------------------------------------------------------------------------
// Fused kernel. grid = 1024 (32 batches x 32 n-blocks), block = 256 = 4 waves.
// Wave owns 128 rows: 4 units of 32 rows (2 groups of 16).
// Depth-~2 rolling prefetch: A buffers even groups, B odd; reload issued
// immediately after consumption so ~1.5 group-chains of latency are covered.
// Per 16-row group: row norm -> bf16 hi/lo frags -> cos MFMA -> softmax ->
//   asg/x^T staged to LDS (transposed layout, pitch 36).
// Per unit: ws MFMA with A(asg),B(x^T) fragments via b64 LDS reads.
// self_product is NOT accumulated: sp[c] == sum_d cn[d,c]*ws[d,c] (identity),
// recovered in k_red1.
// NPART==NB_: non-atomic per-block partials; NPART==1: atomic fallback.
// ---------------------------------------------------------------------------
template<int NPART>
__global__ __launch_bounds__(256, 2) void k_accum(
    const float* __restrict__ x, const float* __restrict__ cent,
    float* __restrict__ wsP)
{
  const int t   = threadIdx.x;
  const int wid = t >> 6;
  const int l   = t & 63;
  const int lm  = l & 15;
  const int lg  = l >> 4;
  const int b   = blockIdx.x >> 5;
  const int nb  = blockIdx.x & 31;

  __shared__ float nrmc[C_];
  __shared__ __align__(16) union {
    struct { unsigned short asg[4][CP_*36]; unsigned short xt[4][64*36]; } m; // 32256 B
    float red[2][CP_*65];                                                     // 24960 B
  } sh;

  if (t < C_) {
    float ss = 0.f;
    for (int d = 0; d < D_; ++d) { float v = cent[d*C_ + t]; ss = fmaf(v, v, ss); }
    nrmc[t] = rsqrtf(fmaxf(ss, 1e-24f));
  }
  __syncthreads();

  // normalized-centroid A-fragments: A[m=c][k=d], c = 16*ct+lm, d = 32*s+8*lg+j
  bf16x8 cnf[3][2];
  #pragma unroll
  for (int ct = 0; ct < 3; ++ct) {
    #pragma unroll
    for (int s = 0; s < 2; ++s) {
      bf16x8 f;
      #pragma unroll
      for (int j = 0; j < 8; ++j) {
        int d = 32*s + 8*lg + j;
        int c = 16*ct + lm;
        float v = (c < C_) ? cent[d*C_ + c] * nrmc[c] : 0.f;
        f[j] = bfbits(v);
      }
      cnf[ct][s] = f;
    }
  }

  f32x4 acc[3][4];
  #pragma unroll
  for (int ct = 0; ct < 3; ++ct)
    #pragma unroll
    for (int nt = 0; nt < 4; ++nt) acc[ct][nt] = (f32x4){0.f,0.f,0.f,0.f};

  unsigned short* aw = sh.m.asg[wid];
  unsigned short* xw = sh.m.xt[wid];

  // per-16-row-group staging: lane holds row lm, float cols {8lg..+7, 32+8lg..+7}
  auto process = [&](float4 c0, float4 c1, float4 c2, float4 c3, int g2) {
    float ss = 0.f;
    ss = fmaf(c0.x,c0.x,ss); ss = fmaf(c0.y,c0.y,ss); ss = fmaf(c0.z,c0.z,ss); ss = fmaf(c0.w,c0.w,ss);
    ss = fmaf(c1.x,c1.x,ss); ss = fmaf(c1.y,c1.y,ss); ss = fmaf(c1.z,c1.z,ss); ss = fmaf(c1.w,c1.w,ss);
    ss = fmaf(c2.x,c2.x,ss); ss = fmaf(c2.y,c2.y,ss); ss = fmaf(c2.z,c2.z,ss); ss = fmaf(c2.w,c2.w,ss);
    ss = fmaf(c3.x,c3.x,ss); ss = fmaf(c3.y,c3.y,ss); ss = fmaf(c3.z,c3.z,ss); ss = fmaf(c3.w,c3.w,ss);
    ss += __shfl_xor(ss, 16);
    ss += __shfl_xor(ss, 32);
    float rn = rsqrtf(fmaxf(ss, 1e-24f));

    bf16x8 bh0, bl0, bh1, bl1;
    CVT1(c0.x,bh0,bl0,0) CVT1(c0.y,bh0,bl0,1) CVT1(c0.z,bh0,bl0,2) CVT1(c0.w,bh0,bl0,3)
    CVT1(c1.x,bh0,bl0,4) CVT1(c1.y,bh0,bl0,5) CVT1(c1.z,bh0,bl0,6) CVT1(c1.w,bh0,bl0,7)
    CVT1(c2.x,bh1,bl1,0) CVT1(c2.y,bh1,bl1,1) CVT1(c2.z,bh1,bl1,2) CVT1(c2.w,bh1,bl1,3)
    CVT1(c3.x,bh1,bl1,4) CVT1(c3.y,bh1,bl1,5) CVT1(c3.z,bh1,bl1,6) CVT1(c3.w,bh1,bl1,7)

    // cos GEMM: D[m=c][n=row] = cn . x (raw x; rn applied in softmax arg)
    f32x4 q0 = (f32x4){0,0,0,0}, q1 = (f32x4){0,0,0,0}, q2 = (f32x4){0,0,0,0};
    q0 = MFMA(cnf[0][0], bh0, q0); q0 = MFMA(cnf[0][1], bh1, q0);
    q0 = MFMA(cnf[0][0], bl0, q0); q0 = MFMA(cnf[0][1], bl1, q0);
    q1 = MFMA(cnf[1][0], bh0, q1); q1 = MFMA(cnf[1][1], bh1, q1);
    q1 = MFMA(cnf[1][0], bl0, q1); q1 = MFMA(cnf[1][1], bl1, q1);
    q2 = MFMA(cnf[2][0], bh0, q2); q2 = MFMA(cnf[2][1], bh1, q2);
    q2 = MFMA(cnf[2][0], bl0, q2); q2 = MFMA(cnf[2][1], bl1, q2);
    f32x4 q[3] = {q0, q1, q2};

    // softmax over c; lane holds c = 16ct+4lg+r for row = lm (+16*g2)
    float e[3][4]; float psum = 0.f;
    #pragma unroll
    for (int ct = 0; ct < 3; ++ct)
      #pragma unroll
      for (int r = 0; r < 4; ++r) {
        int c = 16*ct + 4*lg + r;
        float ev = (c < C_) ? __expf(ALPHA_ * rn * q[ct][r]) : 0.f;
        e[ct][r] = ev; psum += ev;
      }
    psum += __shfl_xor(psum, 16);
    psum += __shfl_xor(psum, 32);
    float arn = rn / psum;               // (assign * rn) scale

    const int rowin = g2*16 + lm;        // row within 32-row unit
    #pragma unroll
    for (int ct = 0; ct < 3; ++ct)
      #pragma unroll
      for (int r = 0; r < 4; ++r)
        aw[(16*ct + 4*lg + r)*36 + rowin] = (unsigned short)bfbits(e[ct][r] * arn);
    #pragma unroll
    for (int j = 0; j < 8; ++j) {
      xw[(     8*lg + j)*36 + rowin] = (unsigned short)bh0[j];     // xt[d][row]
      xw[(32 + 8*lg + j)*36 + rowin] = (unsigned short)bh1[j];
    }
  };

  const float* px = x + ((size_t)b*N_ + (size_t)nb*RPB_ + wid*128 + lm)*D_ + lg*8;

  // A = even-group buffer, B = odd-group buffer; both prefetched at start.
  float4 A0,A1,A2,A3, B0,B1,B2,B3;
  { const float* p = px;        A0=*(const float4*)p; A1=*(const float4*)(p+4); A2=*(const float4*)(p+32); A3=*(const float4*)(p+36); }
  { const float* p = px + 1024; B0=*(const float4*)p; B1=*(const float4*)(p+4); B2=*(const float4*)(p+32); B3=*(const float4*)(p+36); }

  for (int u = 0; u < UNITS_; ++u) {
    process(A0,A1,A2,A3, 0);                       // consume even group 2u
    if (u < UNITS_-1) {                            // issue 2u+2 immediately
      const float* p = px + (size_t)(2*u+2)*1024;
      A0=*(const float4*)p; A1=*(const float4*)(p+4); A2=*(const float4*)(p+32); A3=*(const float4*)(p+36);
    }
    process(B0,B1,B2,B3, 1);                       // consume odd group 2u+1
    if (u < UNITS_-1) {                            // issue 2u+3
      const float* p = px + (size_t)(2*u+3)*1024;
      B0=*(const float4*)p; B1=*(const float4*)(p+4); B2=*(const float4*)(p+32); B3=*(const float4*)(p+36);
    }

    // ws GEMM over this 32-row unit (wave-local LDS, compiler-ordered)
    bf16x8 af0 = ld_frag(&aw[( 0 + lm)*36 + 8*lg]);
    bf16x8 af1 = ld_frag(&aw[(16 + lm)*36 + 8*lg]);
    bf16x8 af2 = ld_frag(&aw[(32 + lm)*36 + 8*lg]);
    #pragma unroll
    for (int nt = 0; nt < 4; ++nt) {
      bf16x8 xf = ld_frag(&xw[(16*nt + lm)*36 + 8*lg]);
      acc[0][nt] = MFMA(af0, xf, acc[0][nt]);
      acc[1][nt] = MFMA(af1, xf, acc[1][nt]);
      acc[2][nt] = MFMA(af2, xf, acc[2][nt]);
    }
  }

  // ---- epilogue: combine 4 waves' acc in LDS, write per-block partials ----
  __syncthreads();                       // all waves done with sh.m (union reuse)
  if (wid < 2) {
    #pragma unroll
    for (int ct = 0; ct < 3; ++ct)
      #pragma unroll
      for (int nt = 0; nt < 4; ++nt)
        #pragma unroll
        for (int r = 0; r < 4; ++r)
          sh.red[wid][(16*ct + 4*lg + r)*65 + 16*nt + lm] = acc[ct][nt][r];
  }
  __syncthreads();
  if (wid >= 2) {
    #pragma unroll
    for (int ct = 0; ct < 3; ++ct)
      #pragma unroll
      for (int nt = 0; nt < 4; ++nt)
        #pragma unroll
        for (int r = 0; r < 4; ++r)
          sh.red[wid-2][(16*ct + 4*lg + r)*65 + 16*nt + lm] += acc[ct][nt][r];
  }
  __syncthreads();

  if (NPART == NB_) {
    const size_t blk = blockIdx.x;
    for (int i = t; i < C_*D_; i += 256) {
      int c = i >> 6, d = i & 63;
      wsP[blk*(C_*D_) + i] = sh.red[0][c*65 + d] + sh.red[1][c*65 + d];
    }
  } else {
    for (int i = t; i < C_*D_; i += 256) {
      int c = i >> 6, d = i & 63;
      atomicAdd(&wsP[(size_t)b*(C_*D_) + i], sh.red[0][c*65 + d] + sh.red[1][c*65 + d]);
    }
  }
}

// ---------------------------------------------------------------------------
// Reduce + finalize: grid = B_*FG_ (1024 blocks), one wave each, for (b, c<32).
// s(d) = sum_k wsP;  sp = sum_d cn(d)*s(d)  [self-product identity];
// v = s - cn*sp;  rc = 1/||v||;  global norm = 1/sqrt(C_) analytically
// (reference normalizes all C_ rows to unit length, so ||flat|| = sqrt(C_)).
// ---------------------------------------------------------------------------
template<int NPART>
__global__ __launch_bounds__(64) void k_red1(
    const float* __restrict__ cent, const float* __restrict__ wsP,
    float* __restrict__ out)
{
  const int bc = blockIdx.x;
  const int b  = bc >> 5;        // / FG_
  const int c  = bc & 31;        // % FG_
  const int d  = threadIdx.x;

  // normalized centroid component cn[d][c]
  float cv = cent[d*C_ + c];
  float cs = cv*cv;
  #pragma unroll
  for (int off = 32; off; off >>= 1) cs += __shfl_xor(cs, off);
  float cn = cv * rsqrtf(fmaxf(cs, 1e-24f));

  // weighted-sum over partials (coalesced across d)
  float s = 0.f;
  #pragma unroll 8
  for (int k = 0; k < NPART; ++k)
    s += wsP[((size_t)b*NPART + k)*(C_*D_) + c*D_ + d];

  // self-product via identity sp = sum_d cn*ws
  float spv = cn * s;
  #pragma unroll
  for (int off = 32; off; off >>= 1) spv += __shfl_xor(spv, off);

  float v = s - cn * spv;
  float vs = v*v;
  #pragma unroll
  for (int off = 32; off; off >>= 1) vs += __shfl_xor(vs, off);

  const float rg = 0.16666666666666666f;   // 1/sqrt(C_): all C_ rows unit-norm
  out[(size_t)bc*D_ + d] = v * rsqrtf(fmaxf(vs, 1e-24f)) * rg;
}

extern "C" void kernel_launch(void* const* d_in, const int* in_sizes, int n_in,
                              void* d_out, int out_size, void* d_ws, size_t ws_size,
                              hipStream_t stream) {
  const float* x    = (const float*)d_in[0];
  const float* cent = (const float*)d_in[1];
  float* out = (float*)d_out;

  const size_t nblk = (size_t)B_ * NB_;                 // 1024
  const size_t need = nblk*(C_*D_) * sizeof(float);     // ~9.4 MB

  if (ws_size >= need) {
    float* wsP = (float*)d_ws;                          // [1024][2304]
    k_accum<NB_><<<B_*NB_, 256, 0, stream>>>(x, cent, wsP);
    k_red1<NB_><<<B_*FG_, 64, 0, stream>>>(cent, wsP, out);
  } else {                                              // atomic fallback
    float* wsA = (float*)d_ws;                          // [32][2304]
    hipMemsetAsync(d_ws, 0, (size_t)B_*(C_*D_)*sizeof(float), stream);
    k_accum<1><<<B_*NB_, 256, 0, stream>>>(x, cent, wsA);
    k_red1<1><<<B_*FG_, 64, 0, stream>>>(cent, wsA, out);
  }
}